// Round 9
// baseline (758.310 us; speedup 1.0000x reference)
//
#include <hip/hip_runtime.h>
#include <hip/hip_bf16.h>
#include <stdint.h>

// ============================================================================
// Transformer-XL relative attention, MI355X / gfx950.
// merged weight transpose -> Q/KV/R projection GEMMs (bf16 MFMA, fp32 accum,
// 2-phase double-buffered staging) -> V transpose -> flash attention with
// rel-shift band trick (single-buffer, 4 blocks/CU, defer-max, ones-MFMA
// denominator) -> out GEMM.
// rel_shift(BD)[i,j] == BD[i, j + QLEN-1-i]; OOB exactly == masked region.
// q/qr are PRE-SCALED by (1/8)*log2(e) at projection time.
// ============================================================================

#define DEVI static __device__ __forceinline__

typedef __attribute__((ext_vector_type(8))) short  s8v;   // 8 x bf16 (4 VGPR)
typedef __attribute__((ext_vector_type(4))) float  f4v;
typedef __attribute__((ext_vector_type(2))) int    i2v;
typedef __attribute__((ext_vector_type(4))) float  fl4;

DEVI unsigned short f2b(float f) {
  __hip_bfloat16 h = __float2bfloat16(f);
  return __builtin_bit_cast(unsigned short, h);
}

DEVI f4v MFMA(s8v a, s8v b, f4v c) {
  return __builtin_amdgcn_mfma_f32_16x16x32_bf16(a, b, c, 0, 0, 0);
}

// async global->LDS, 16B per lane. lds ptr must be wave-uniform base;
// HW adds lane*16. Global address is per-lane.
DEVI void gl_lds16(const void* g, void* lds) {
  __builtin_amdgcn_global_load_lds(
      (const __attribute__((address_space(1))) unsigned int*)g,
      (__attribute__((address_space(3))) unsigned int*)lds, 16, 0, 0);
}

// ---------------------------------------------------------------------------
// Merged transpose + bf16 convert for all four weights:
// W [1024=K][N] fp32 -> WT [N][1024] bf16. grid.x ranges select the matrix.
// ---------------------------------------------------------------------------
__global__ void transpose_all(const float* __restrict__ Wq,
                              const float* __restrict__ Wkv,
                              const float* __restrict__ Wr,
                              const float* __restrict__ Wo,
                              unsigned short* __restrict__ WqT,
                              unsigned short* __restrict__ WkvT,
                              unsigned short* __restrict__ WrT,
                              unsigned short* __restrict__ WoT) {
  __shared__ float tile[32][33];
  const int bx = blockIdx.x;
  const float* W;
  unsigned short* WT;
  int N, nb;
  if (bx < 32)       { W = Wq;  WT = WqT;  N = 1024; nb = bx; }
  else if (bx < 96)  { W = Wkv; WT = WkvT; N = 2048; nb = bx - 32; }
  else if (bx < 128) { W = Wr;  WT = WrT;  N = 1024; nb = bx - 96; }
  else               { W = Wo;  WT = WoT;  N = 1024; nb = bx - 128; }
  int n0 = nb * 32, k0 = blockIdx.y * 32;
  int tx = threadIdx.x, ty = threadIdx.y;  // 32 x 8
#pragma unroll
  for (int i = 0; i < 4; ++i)
    tile[ty + i * 8][tx] = W[(size_t)(k0 + ty + i * 8) * N + n0 + tx];
  __syncthreads();
#pragma unroll
  for (int i = 0; i < 4; ++i)
    WT[(size_t)(n0 + ty + i * 8) * 1024 + k0 + tx] = f2b(tile[tx][ty + i * 8]);
}

// ---------------------------------------------------------------------------
// V transpose: vbf [bh][2048 j][64 d] bf16 -> vt [bh][64 d][2048 j] bf16
// ---------------------------------------------------------------------------
__global__ void transpose_v(const unsigned short* __restrict__ in,
                            unsigned short* __restrict__ out) {
  __shared__ unsigned short Ts[64 * 72];
  const int t = threadIdx.x;
  const int j0 = blockIdx.x * 64;
  const size_t bh = blockIdx.y;
#pragma unroll
  for (int p = 0; p < 2; ++p) {
    int cc = t + p * 256;  // chunk id 0..511
    int j = cc >> 3, d0 = (cc & 7) * 8;
    s8v v = *(const s8v*)(in + (bh * 2048 + j0 + j) * 64 + d0);
    *(s8v*)(Ts + j * 72 + d0) = v;
  }
  __syncthreads();
  const int d = t >> 2, jc = (t & 3) * 16;
  s8v a, b;
#pragma unroll
  for (int e = 0; e < 8; ++e) a[e] = (short)Ts[(jc + e) * 72 + d];
#pragma unroll
  for (int e = 0; e < 8; ++e) b[e] = (short)Ts[(jc + 8 + e) * 72 + d];
  *(s8v*)(out + (bh * 64 + d) * 2048 + j0 + jc) = a;
  *(s8v*)(out + (bh * 64 + d) * 2048 + j0 + jc + 8) = b;
}

// ---------------------------------------------------------------------------
// GEMM: C[M][N] = A[M][1024] * B, B given as BT[N][1024] bf16.
// MODE 0: A=w tail rows, out qw/qr bf16 per-(b,head) [i][d] (+biases, *QSC)
// MODE 1: A=w,        out k/v bf16 per-(b,head) [j][d]
// MODE 2: A=r,        out rk bf16 per-head [m][d]
// MODE 3: A=attn_vec bf16, out fp32 d_out
// 128x128 tile, BK=32, 256 threads (4 waves, 2x2), 16x16x32 MFMA.
// 2-phase: stage(t+1) issued before compute(t); one barrier per K-step.
// ---------------------------------------------------------------------------
template <int MODE>
__global__ __launch_bounds__(256, 2) void gemm_kern(
    const float* __restrict__ A, const unsigned short* __restrict__ A16,
    const unsigned short* __restrict__ BT, unsigned short* __restrict__ O1,
    unsigned short* __restrict__ O2, float* __restrict__ Of,
    const float* __restrict__ biasw, const float* __restrict__ biasr) {
  __shared__ unsigned short As[2][128 * 32];
  __shared__ unsigned short Bs[2][128 * 32];
  const int t = threadIdx.x, l = t & 63, w = t >> 6;
  const int g = l >> 4, lr = l & 15;
  const int bm = blockIdx.x, bn = blockIdx.y;
  const int wr = w >> 1, wc = w & 1;
  const float QSC = 0.18033688f;  // (1/sqrt(64)) * log2(e)
  f4v acc[4][4] = {};

  auto stageB = [&](int k0, int buf) {
#pragma unroll
    for (int ss = 0; ss < 2; ++ss) {
      int idx = w * 64 + ss * 256 + l;
      int row = idx >> 2, c = idx & 3;
      gl_lds16(BT + (size_t)(bn * 128 + row) * 1024 + k0 + c * 8,
               (void*)(Bs[buf] + (w * 64 + ss * 256) * 8));
    }
  };
  auto stageA_lds = [&](int k0, int buf) {
#pragma unroll
    for (int ss = 0; ss < 2; ++ss) {
      int idx = w * 64 + ss * 256 + l;
      int row = idx >> 2, c = idx & 3;
      gl_lds16(A16 + (size_t)(bm * 128 + row) * 1024 + k0 + c * 8,
               (void*)(As[buf] + (w * 64 + ss * 256) * 8));
    }
  };
  auto loadA = [&](int k0, fl4* regs) {
#pragma unroll
    for (int ss = 0; ss < 4; ++ss) {
      int idx = t + ss * 256;
      int row = idx >> 3, c = idx & 7;
      int grow = bm * 128 + row;
      size_t arow = (MODE == 0)
                        ? ((size_t)(grow >> 10) * 2048 + 1024 + (grow & 1023))
                        : (size_t)grow;
      regs[ss] = *(const fl4*)(A + arow * 1024 + k0 + c * 4);
    }
  };
  auto writeA = [&](const fl4* regs, int buf) {
#pragma unroll
    for (int ss = 0; ss < 4; ++ss) {
      int idx = t + ss * 256;
      int row = idx >> 3, c = idx & 7;
      fl4 v = regs[ss];
      unsigned int p0 = f2b(v.x) | ((unsigned int)f2b(v.y) << 16);
      unsigned int p1 = f2b(v.z) | ((unsigned int)f2b(v.w) << 16);
      i2v pv; pv.x = (int)p0; pv.y = (int)p1;
      *(i2v*)(As[buf] + row * 32 + c * 4) = pv;
    }
  };

  // ---- prologue: stage k0=0 into buf 0 ----
  stageB(0, 0);
  if (MODE == 3) {
    stageA_lds(0, 0);
  } else {
    fl4 r0[4];
    loadA(0, r0);
    writeA(r0, 0);
  }
  __syncthreads();

  int cur = 0;
  for (int step = 0; step < 32; ++step) {
    const bool nx = step < 31;
    const int nk0 = (step + 1) * 32;
    fl4 aregs[4];
    if (nx) {
      stageB(nk0, cur ^ 1);
      if (MODE == 3) stageA_lds(nk0, cur ^ 1);
      else loadA(nk0, aregs);
    }
    s8v af[4], bf[4];
#pragma unroll
    for (int m = 0; m < 4; ++m)
      af[m] = *(const s8v*)(As[cur] + (wr * 64 + m * 16 + lr) * 32 + g * 8);
#pragma unroll
    for (int n = 0; n < 4; ++n)
      bf[n] = *(const s8v*)(Bs[cur] + (wc * 64 + n * 16 + lr) * 32 + g * 8);
#pragma unroll
    for (int m = 0; m < 4; ++m)
#pragma unroll
      for (int n = 0; n < 4; ++n) acc[m][n] = MFMA(af[m], bf[n], acc[m][n]);
    if (nx && MODE != 3) writeA(aregs, cur ^ 1);
    __syncthreads();
    cur ^= 1;
  }

  // ---- epilogue ----
#pragma unroll
  for (int m = 0; m < 4; ++m) {
#pragma unroll
    for (int n = 0; n < 4; ++n) {
#pragma unroll
      for (int r = 0; r < 4; ++r) {
        int row = bm * 128 + wr * 64 + m * 16 + g * 4 + r;
        int col = bn * 128 + wc * 64 + n * 16 + lr;
        float v = acc[m][n][r];
        if (MODE == 0) {
          int b = row >> 10, i = row & 1023;
          int nh = col >> 6, d = col & 63;
          size_t o = ((size_t)(b * 16 + nh) * 1024 + i) * 64 + d;
          O1[o] = f2b((v + biasw[col]) * QSC);
          O2[o] = f2b((v + biasr[col]) * QSC);
        } else if (MODE == 1) {
          int b = row >> 11, j = row & 2047;
          if (col < 1024)
            O1[((size_t)(b * 16 + (col >> 6)) * 2048 + j) * 64 + (col & 63)] =
                f2b(v);
          else
            O2[((size_t)(b * 16 + ((col - 1024) >> 6)) * 2048 + j) * 64 +
               (col & 63)] = f2b(v);
        } else if (MODE == 2) {
          O1[((size_t)(col >> 6) * 2048 + row) * 64 + (col & 63)] = f2b(v);
        } else {
          Of[(size_t)row * 1024 + col] = v;
        }
      }
    }
  }
}

// ---------------------------------------------------------------------------
// Flash attention with rel-shift. Block = (i0 block of 64 q-rows, head, batch).
// 4 waves x 16 q-rows, single-buffered staging, 4 blocks/CU.
// Per 64-wide j-tile:
//   AC = qw . K^T          (K LDS [j][d], chunk-XOR swizzled)
//   E  = qr . rk[m0..m0+127]^T, per-wave 5 frags (80-wide band)
//   score = AC + shifted E (q pre-scaled); defer-max online softmax
//   P -> per-wave LDS [16 i][64 j] (swizzled); O += P.V; l via ones-MFMA
// m0 = j0 + 960 - i0; clamp m<=2047 (active only on final tile == masked).
// i0 swizzled (bx*5 mod 16) for CU work balance (ntile varies 17..32).
// ---------------------------------------------------------------------------
__global__ __launch_bounds__(256, 4) void attn_kern(
    const unsigned short* __restrict__ qw, const unsigned short* __restrict__ qr,
    const unsigned short* __restrict__ kk, const unsigned short* __restrict__ vt,
    const unsigned short* __restrict__ rkp, unsigned short* __restrict__ av) {
  __shared__ unsigned short Ks[64 * 64];   // [j][d], chunk-XOR swizzled
  __shared__ unsigned short Vs[64 * 64];   // [d][j] (V^T tile), swizzled
  __shared__ unsigned short Rs[128 * 64];  // [m][d], swizzled
  __shared__ unsigned short Pn[4][1024];   // per-wave P [16 i][64 j], swz
  const int t = threadIdx.x, l = t & 63, w = t >> 6;
  const int g = l >> 4, lr = l & 15;
  const int i0 = ((blockIdx.x * 5) & 15) * 64;  // work-balance swizzle
  const int n = blockIdx.y, b = blockIdx.z;
  const size_t bn = (size_t)(b * 16 + n);
  const unsigned short* qwb = qw + bn * 1024 * 64;
  const unsigned short* qrb = qr + bn * 1024 * 64;
  const unsigned short* kb = kk + bn * 2048 * 64;
  const unsigned short* vb = vt + bn * 64 * 2048;
  const unsigned short* rb = rkp + (size_t)n * 2048 * 64;

  // resident Q fragments (A-operand: row = lr, k = g*8+e); pre-scaled by QSC
  const int qi = i0 + w * 16 + lr;
  s8v aqw[2], aqr[2];
#pragma unroll
  for (int ks = 0; ks < 2; ++ks) {
    aqw[ks] = *(const s8v*)(qwb + (size_t)qi * 64 + ks * 32 + g * 8);
    aqr[ks] = *(const s8v*)(qrb + (size_t)qi * 64 + ks * 32 + g * 8);
  }

  // all-ones bf16 B fragment for the denominator MFMA
  s8v ONES;
#pragma unroll
  for (int e = 0; e < 8; ++e) ONES[e] = (short)0x3F80;

  f4v acco[4] = {};
  f4v accl = {};                       // softmax denominator (replicated/lane)
  float mrow[4] = {-3e38f, -3e38f, -3e38f, -3e38f};

  const int ntile = (i0 + 1088) >> 6;

  auto stage = [&](int jt) {
    const int j0 = jt * 64;
    const int m0 = j0 + 960 - i0;
    // K [j][d]
#pragma unroll
    for (int ss = 0; ss < 2; ++ss) {
      int idx = w * 64 + ss * 256 + l;
      int row = idx >> 3, c = idx & 7;
      gl_lds16(kb + (size_t)(j0 + row) * 64 + ((c ^ (row & 7)) * 8),
               (void*)(Ks + (w * 64 + ss * 256) * 8));
    }
    // V^T [d][j]
#pragma unroll
    for (int ss = 0; ss < 2; ++ss) {
      int idx = w * 64 + ss * 256 + l;
      int d = idx >> 3, c = idx & 7;
      gl_lds16(vb + (size_t)d * 2048 + j0 + ((c ^ (d & 7)) * 8),
               (void*)(Vs + (w * 64 + ss * 256) * 8));
    }
    // RK band [m0..m0+127][d]
#pragma unroll
    for (int ss = 0; ss < 4; ++ss) {
      int idx = w * 64 + ss * 256 + l;
      int rr = idx >> 3, c = idx & 7;
      int m = m0 + rr;
      if (m > 2047) m = 2047;
      gl_lds16(rb + (size_t)m * 64 + ((c ^ (rr & 7)) * 8),
               (void*)(Rs + (w * 64 + ss * 256) * 8));
    }
  };

  for (int jt = 0; jt < ntile; ++jt) {
    const int j0 = jt * 64;
    stage(jt);
    __syncthreads();
    const bool mt = (jt == ntile - 1);  // only final tile can mask

    // ---- AC and E MFMAs ----
    f4v accs[4] = {};
    f4v acce[5] = {};
#pragma unroll
    for (int ks = 0; ks < 2; ++ks) {
#pragma unroll
      for (int jf = 0; jf < 4; ++jf) {
        int row = jf * 16 + lr;
        s8v bk =
            *(const s8v*)(Ks + row * 64 + (((ks * 4 + g) ^ (row & 7)) * 8));
        accs[jf] = MFMA(aqw[ks], bk, accs[jf]);
      }
#pragma unroll
      for (int ef = 0; ef < 5; ++ef) {
        int row = (3 - w + ef) * 16 + lr;
        s8v br =
            *(const s8v*)(Rs + row * 64 + (((ks * 4 + g) ^ (row & 7)) * 8));
        acce[ef] = MFMA(aqr[ks], br, acce[ef]);
      }
    }

    // ---- shift-extract E (5 dedup'd shuffles), defer-max softmax ----
    // score lane (g,lr), reg r: i = i0+w*16+4g+r, j = j0+jf*16+lr.
    // band row rr = (3-w+jf+carry)*16 + ((lr+s)&15), s = 15-4g-r.
    float P[4][4];
#pragma unroll
    for (int r = 0; r < 4; ++r) {
      const int s = 15 - 4 * g - r;           // in [0,15]
      const int src = (l & 48) | ((lr + s) & 15);
      const int carry = (lr + s) >> 4;
      float es[5];
#pragma unroll
      for (int f = 0; f < 5; ++f) es[f] = __shfl(acce[f][r], src, 64);
      float pmax = -3e38f;
#pragma unroll
      for (int jf = 0; jf < 4; ++jf) {
        float sv = accs[jf][r] + (carry ? es[jf + 1] : es[jf]);
        if (mt) {
          int jg = j0 + jf * 16 + lr;
          int ig = i0 + w * 16 + 4 * g + r;
          if (jg > ig + 1024) sv = -3e38f;
        }
        P[jf][r] = sv;
        pmax = fmaxf(pmax, sv);
      }
      if (!__all(pmax <= mrow[r] + 8.0f)) {   // rare after first tile
        float rmax = pmax;
#pragma unroll
        for (int dd = 1; dd < 16; dd <<= 1)
          rmax = fmaxf(rmax, __shfl_xor(rmax, dd, 64));
        float nm = fmaxf(mrow[r], rmax);
        float corr = exp2f(mrow[r] - nm);
        mrow[r] = nm;
#pragma unroll
        for (int df = 0; df < 4; ++df) acco[df][r] *= corr;
        accl[r] *= corr;
      }
#pragma unroll
      for (int jf = 0; jf < 4; ++jf) P[jf][r] = exp2f(P[jf][r] - mrow[r]);
    }

    // ---- P -> per-wave LDS [16 i][64 j], chunk-XOR swizzled ----
#pragma unroll
    for (int jf = 0; jf < 4; ++jf) {
#pragma unroll
      for (int r = 0; r < 4; ++r) {
        int ip = 4 * g + r;
        int cj = (jf * 2 + (lr >> 3)) ^ (ip & 7);
        Pn[w][ip * 64 + cj * 8 + (lr & 7)] = f2b(P[jf][r]);
      }
    }
    asm volatile("s_waitcnt lgkmcnt(0)" ::: "memory");
    __builtin_amdgcn_sched_barrier(0);

    // ---- PV + denominator: standard A/B fragment reads ----
#pragma unroll
    for (int ks = 0; ks < 2; ++ks) {
      s8v ap =
          *(const s8v*)(Pn[w] + lr * 64 + (((ks * 4 + g) ^ (lr & 7)) * 8));
      accl = MFMA(ap, ONES, accl);     // row-sum of P, replicated per lane
#pragma unroll
      for (int df = 0; df < 4; ++df) {
        int vrow = df * 16 + lr;
        s8v bv = *(const s8v*)(Vs + vrow * 64 +
                               (((ks * 4 + g) ^ (vrow & 7)) * 8));
        acco[df] = MFMA(ap, bv, acco[df]);
      }
    }
    __syncthreads();  // Ks/Vs/Rs/Pn safe to overwrite next tile
  }

  // ---- epilogue: O / l -> attn_vec bf16 [b*1024+i][n*64+d] ----
#pragma unroll
  for (int r = 0; r < 4; ++r) {
    float inv = 1.0f / accl[r];
    int ig = i0 + w * 16 + 4 * g + r;
#pragma unroll
    for (int df = 0; df < 4; ++df)
      av[((size_t)b * 1024 + ig) * 1024 + n * 64 + df * 16 + lr] =
          f2b(acco[df][r] * inv);
  }
}

// ---------------------------------------------------------------------------
extern "C" void kernel_launch(void* const* d_in, const int* in_sizes, int n_in,
                              void* d_out, int out_size, void* d_ws,
                              size_t ws_size, hipStream_t stream) {
  (void)in_sizes; (void)n_in; (void)out_size; (void)ws_size;
  const float* w   = (const float*)d_in[0];
  const float* r   = (const float*)d_in[1];
  const float* Wq  = (const float*)d_in[2];
  const float* Wkv = (const float*)d_in[3];
  const float* Wr  = (const float*)d_in[4];
  const float* Wo  = (const float*)d_in[5];
  const float* bw  = (const float*)d_in[6];
  const float* br  = (const float*)d_in[7];

  char* ws = (char*)d_ws;
  const size_t MB = 1024 * 1024;
  unsigned short* WqT  = (unsigned short*)(ws + 0 * MB);   // 2MB
  unsigned short* WkvT = (unsigned short*)(ws + 2 * MB);   // 4MB
  unsigned short* WrT  = (unsigned short*)(ws + 6 * MB);   // 2MB
  unsigned short* WoT  = (unsigned short*)(ws + 8 * MB);   // 2MB
  unsigned short* qwb  = (unsigned short*)(ws + 10 * MB);  // 8MB
  unsigned short* qrb  = (unsigned short*)(ws + 18 * MB);  // 8MB
  unsigned short* kbf  = (unsigned short*)(ws + 26 * MB);  // 16MB
  unsigned short* vbf  = (unsigned short*)(ws + 42 * MB);  // 16MB
  unsigned short* rkb  = (unsigned short*)(ws + 58 * MB);  // 4MB
  unsigned short* avb  = (unsigned short*)(ws + 62 * MB);  // 8MB (end 70MB)
  // V^T scratch: reuse d_out (16MB fp32 == 16MB needed; dead until gemm<3>).
  unsigned short* vtb  = (unsigned short*)d_out;

  hipLaunchKernelGGL(transpose_all, dim3(160, 32), dim3(32, 8), 0, stream,
                     Wq, Wkv, Wr, Wo, WqT, WkvT, WrT, WoT);

  hipLaunchKernelGGL((gemm_kern<0>), dim3(32, 8), dim3(256), 0, stream,
                     w, (const unsigned short*)nullptr, WqT, qwb, qrb,
                     (float*)nullptr, bw, br);
  hipLaunchKernelGGL((gemm_kern<1>), dim3(64, 16), dim3(256), 0, stream,
                     w, (const unsigned short*)nullptr, WkvT, kbf, vbf,
                     (float*)nullptr, (const float*)nullptr,
                     (const float*)nullptr);
  hipLaunchKernelGGL((gemm_kern<2>), dim3(16, 8), dim3(256), 0, stream,
                     r, (const unsigned short*)nullptr, WrT, rkb,
                     (unsigned short*)nullptr, (float*)nullptr,
                     (const float*)nullptr, (const float*)nullptr);

  hipLaunchKernelGGL(transpose_v, dim3(32, 64), dim3(256), 0, stream, vbf, vtb);

  hipLaunchKernelGGL(attn_kern, dim3(16, 16, 4), dim3(256), 0, stream,
                     qwb, qrb, kbf, vtb, rkb, avb);

  hipLaunchKernelGGL((gemm_kern<3>), dim3(32, 8), dim3(256), 0, stream,
                     (const float*)nullptr, avb, WoT, (unsigned short*)nullptr,
                     (unsigned short*)nullptr, (float*)d_out,
                     (const float*)nullptr, (const float*)nullptr);
}

// Round 12
// 495.334 us; speedup vs baseline: 1.5309x; 1.5309x over previous
//
#include <hip/hip_runtime.h>
#include <hip/hip_bf16.h>
#include <stdint.h>

// ============================================================================
// Transformer-XL relative attention, MI355X / gfx950.
// merged weight transpose -> Q/KV/R projection GEMMs (bf16 MFMA, fp32 accum,
// 2-phase double-buffered staging) -> V transpose -> flash attention with
// rel-shift band trick (single-buffer, defer-max, ones-MFMA denominator)
// -> out GEMM.
// rel_shift(BD)[i,j] == BD[i, j + QLEN-1-i]; OOB exactly == masked region.
// q/qr are PRE-SCALED by (1/8)*log2(e) at projection time.
// NOTE: attn launch_bounds must stay (256,2) -- (256,4) forces VGPR=64 and
// ~840MB of scratch spill traffic per dispatch (round-9 regression).
// ============================================================================

#define DEVI static __device__ __forceinline__

typedef __attribute__((ext_vector_type(8))) short  s8v;   // 8 x bf16 (4 VGPR)
typedef __attribute__((ext_vector_type(4))) float  f4v;
typedef __attribute__((ext_vector_type(2))) int    i2v;
typedef __attribute__((ext_vector_type(4))) float  fl4;

DEVI unsigned short f2b(float f) {
  __hip_bfloat16 h = __float2bfloat16(f);
  return __builtin_bit_cast(unsigned short, h);
}

DEVI f4v MFMA(s8v a, s8v b, f4v c) {
  return __builtin_amdgcn_mfma_f32_16x16x32_bf16(a, b, c, 0, 0, 0);
}

// async global->LDS, 16B per lane. lds ptr must be wave-uniform base;
// HW adds lane*16. Global address is per-lane.
DEVI void gl_lds16(const void* g, void* lds) {
  __builtin_amdgcn_global_load_lds(
      (const __attribute__((address_space(1))) unsigned int*)g,
      (__attribute__((address_space(3))) unsigned int*)lds, 16, 0, 0);
}

// ---------------------------------------------------------------------------
// Merged transpose + bf16 convert for all four weights:
// W [1024=K][N] fp32 -> WT [N][1024] bf16. grid.x ranges select the matrix.
// ---------------------------------------------------------------------------
__global__ void transpose_all(const float* __restrict__ Wq,
                              const float* __restrict__ Wkv,
                              const float* __restrict__ Wr,
                              const float* __restrict__ Wo,
                              unsigned short* __restrict__ WqT,
                              unsigned short* __restrict__ WkvT,
                              unsigned short* __restrict__ WrT,
                              unsigned short* __restrict__ WoT) {
  __shared__ float tile[32][33];
  const int bx = blockIdx.x;
  const float* W;
  unsigned short* WT;
  int N, nb;
  if (bx < 32)       { W = Wq;  WT = WqT;  N = 1024; nb = bx; }
  else if (bx < 96)  { W = Wkv; WT = WkvT; N = 2048; nb = bx - 32; }
  else if (bx < 128) { W = Wr;  WT = WrT;  N = 1024; nb = bx - 96; }
  else               { W = Wo;  WT = WoT;  N = 1024; nb = bx - 128; }
  int n0 = nb * 32, k0 = blockIdx.y * 32;
  int tx = threadIdx.x, ty = threadIdx.y;  // 32 x 8
#pragma unroll
  for (int i = 0; i < 4; ++i)
    tile[ty + i * 8][tx] = W[(size_t)(k0 + ty + i * 8) * N + n0 + tx];
  __syncthreads();
#pragma unroll
  for (int i = 0; i < 4; ++i)
    WT[(size_t)(n0 + ty + i * 8) * 1024 + k0 + tx] = f2b(tile[tx][ty + i * 8]);
}

// ---------------------------------------------------------------------------
// V transpose: vbf [bh][2048 j][64 d] bf16 -> vt [bh][64 d][2048 j] bf16
// ---------------------------------------------------------------------------
__global__ void transpose_v(const unsigned short* __restrict__ in,
                            unsigned short* __restrict__ out) {
  __shared__ unsigned short Ts[64 * 72];
  const int t = threadIdx.x;
  const int j0 = blockIdx.x * 64;
  const size_t bh = blockIdx.y;
#pragma unroll
  for (int p = 0; p < 2; ++p) {
    int cc = t + p * 256;  // chunk id 0..511
    int j = cc >> 3, d0 = (cc & 7) * 8;
    s8v v = *(const s8v*)(in + (bh * 2048 + j0 + j) * 64 + d0);
    *(s8v*)(Ts + j * 72 + d0) = v;
  }
  __syncthreads();
  const int d = t >> 2, jc = (t & 3) * 16;
  s8v a, b;
#pragma unroll
  for (int e = 0; e < 8; ++e) a[e] = (short)Ts[(jc + e) * 72 + d];
#pragma unroll
  for (int e = 0; e < 8; ++e) b[e] = (short)Ts[(jc + 8 + e) * 72 + d];
  *(s8v*)(out + (bh * 64 + d) * 2048 + j0 + jc) = a;
  *(s8v*)(out + (bh * 64 + d) * 2048 + j0 + jc + 8) = b;
}

// ---------------------------------------------------------------------------
// GEMM: C[M][N] = A[M][1024] * B, B given as BT[N][1024] bf16.
// MODE 0: A=w tail rows, out qw/qr bf16 per-(b,head) [i][d] (+biases, *QSC)
// MODE 1: A=w,        out k/v bf16 per-(b,head) [j][d]
// MODE 2: A=r,        out rk bf16 per-head [m][d]
// MODE 3: A=attn_vec bf16, out fp32 d_out
// 128x128 tile, BK=32, 256 threads (4 waves, 2x2), 16x16x32 MFMA.
// 2-phase: stage(t+1) issued before compute(t); one barrier per K-step.
// ---------------------------------------------------------------------------
template <int MODE>
__global__ __launch_bounds__(256, 2) void gemm_kern(
    const float* __restrict__ A, const unsigned short* __restrict__ A16,
    const unsigned short* __restrict__ BT, unsigned short* __restrict__ O1,
    unsigned short* __restrict__ O2, float* __restrict__ Of,
    const float* __restrict__ biasw, const float* __restrict__ biasr) {
  __shared__ unsigned short As[2][128 * 32];
  __shared__ unsigned short Bs[2][128 * 32];
  const int t = threadIdx.x, l = t & 63, w = t >> 6;
  const int g = l >> 4, lr = l & 15;
  const int bm = blockIdx.x, bn = blockIdx.y;
  const int wr = w >> 1, wc = w & 1;
  const float QSC = 0.18033688f;  // (1/sqrt(64)) * log2(e)
  f4v acc[4][4] = {};

  auto stageB = [&](int k0, int buf) {
#pragma unroll
    for (int ss = 0; ss < 2; ++ss) {
      int idx = w * 64 + ss * 256 + l;
      int row = idx >> 2, c = idx & 3;
      gl_lds16(BT + (size_t)(bn * 128 + row) * 1024 + k0 + c * 8,
               (void*)(Bs[buf] + (w * 64 + ss * 256) * 8));
    }
  };
  auto stageA_lds = [&](int k0, int buf) {
#pragma unroll
    for (int ss = 0; ss < 2; ++ss) {
      int idx = w * 64 + ss * 256 + l;
      int row = idx >> 2, c = idx & 3;
      gl_lds16(A16 + (size_t)(bm * 128 + row) * 1024 + k0 + c * 8,
               (void*)(As[buf] + (w * 64 + ss * 256) * 8));
    }
  };
  auto loadA = [&](int k0, fl4* regs) {
#pragma unroll
    for (int ss = 0; ss < 4; ++ss) {
      int idx = t + ss * 256;
      int row = idx >> 3, c = idx & 7;
      int grow = bm * 128 + row;
      size_t arow = (MODE == 0)
                        ? ((size_t)(grow >> 10) * 2048 + 1024 + (grow & 1023))
                        : (size_t)grow;
      regs[ss] = *(const fl4*)(A + arow * 1024 + k0 + c * 4);
    }
  };
  auto writeA = [&](const fl4* regs, int buf) {
#pragma unroll
    for (int ss = 0; ss < 4; ++ss) {
      int idx = t + ss * 256;
      int row = idx >> 3, c = idx & 7;
      fl4 v = regs[ss];
      unsigned int p0 = f2b(v.x) | ((unsigned int)f2b(v.y) << 16);
      unsigned int p1 = f2b(v.z) | ((unsigned int)f2b(v.w) << 16);
      i2v pv; pv.x = (int)p0; pv.y = (int)p1;
      *(i2v*)(As[buf] + row * 32 + c * 4) = pv;
    }
  };

  // ---- prologue: stage k0=0 into buf 0 ----
  stageB(0, 0);
  if (MODE == 3) {
    stageA_lds(0, 0);
  } else {
    fl4 r0[4];
    loadA(0, r0);
    writeA(r0, 0);
  }
  __syncthreads();

  int cur = 0;
  for (int step = 0; step < 32; ++step) {
    const bool nx = step < 31;
    const int nk0 = (step + 1) * 32;
    fl4 aregs[4];
    if (nx) {
      stageB(nk0, cur ^ 1);
      if (MODE == 3) stageA_lds(nk0, cur ^ 1);
      else loadA(nk0, aregs);
    }
    s8v af[4], bf[4];
#pragma unroll
    for (int m = 0; m < 4; ++m)
      af[m] = *(const s8v*)(As[cur] + (wr * 64 + m * 16 + lr) * 32 + g * 8);
#pragma unroll
    for (int n = 0; n < 4; ++n)
      bf[n] = *(const s8v*)(Bs[cur] + (wc * 64 + n * 16 + lr) * 32 + g * 8);
#pragma unroll
    for (int m = 0; m < 4; ++m)
#pragma unroll
      for (int n = 0; n < 4; ++n) acc[m][n] = MFMA(af[m], bf[n], acc[m][n]);
    if (nx && MODE != 3) writeA(aregs, cur ^ 1);
    __syncthreads();
    cur ^= 1;
  }

  // ---- epilogue ----
#pragma unroll
  for (int m = 0; m < 4; ++m) {
#pragma unroll
    for (int n = 0; n < 4; ++n) {
#pragma unroll
      for (int r = 0; r < 4; ++r) {
        int row = bm * 128 + wr * 64 + m * 16 + g * 4 + r;
        int col = bn * 128 + wc * 64 + n * 16 + lr;
        float v = acc[m][n][r];
        if (MODE == 0) {
          int b = row >> 10, i = row & 1023;
          int nh = col >> 6, d = col & 63;
          size_t o = ((size_t)(b * 16 + nh) * 1024 + i) * 64 + d;
          O1[o] = f2b((v + biasw[col]) * QSC);
          O2[o] = f2b((v + biasr[col]) * QSC);
        } else if (MODE == 1) {
          int b = row >> 11, j = row & 2047;
          if (col < 1024)
            O1[((size_t)(b * 16 + (col >> 6)) * 2048 + j) * 64 + (col & 63)] =
                f2b(v);
          else
            O2[((size_t)(b * 16 + ((col - 1024) >> 6)) * 2048 + j) * 64 +
               (col & 63)] = f2b(v);
        } else if (MODE == 2) {
          O1[((size_t)(col >> 6) * 2048 + row) * 64 + (col & 63)] = f2b(v);
        } else {
          Of[(size_t)row * 1024 + col] = v;
        }
      }
    }
  }
}

// ---------------------------------------------------------------------------
// Flash attention with rel-shift. Block = (i0 block of 64 q-rows, head, batch).
// 4 waves x 16 q-rows, single-buffered staging.
// Per 64-wide j-tile:
//   AC = qw . K^T          (K LDS [j][d], chunk-XOR swizzled)
//   E  = qr . rk[m0..m0+127]^T, per-wave 5 frags (80-wide band)
//   score = AC + shifted E (q pre-scaled); defer-max online softmax
//   P -> per-wave LDS [16 i][64 j] (swizzled); O += P.V; l via ones-MFMA
// m0 = j0 + 960 - i0; clamp m<=2047 (active only on final tile == masked).
// i0 swizzled (bx*5 mod 16) for CU work balance (ntile varies 17..32).
// launch_bounds (256,2): DO NOT raise -- (256,4) caps VGPR at 64 and spills.
// ---------------------------------------------------------------------------
__global__ __launch_bounds__(256, 2) void attn_kern(
    const unsigned short* __restrict__ qw, const unsigned short* __restrict__ qr,
    const unsigned short* __restrict__ kk, const unsigned short* __restrict__ vt,
    const unsigned short* __restrict__ rkp, unsigned short* __restrict__ av) {
  __shared__ unsigned short Ks[64 * 64];   // [j][d], chunk-XOR swizzled
  __shared__ unsigned short Vs[64 * 64];   // [d][j] (V^T tile), swizzled
  __shared__ unsigned short Rs[128 * 64];  // [m][d], swizzled
  __shared__ unsigned short Pn[4][1024];   // per-wave P [16 i][64 j], swz
  const int t = threadIdx.x, l = t & 63, w = t >> 6;
  const int g = l >> 4, lr = l & 15;
  const int i0 = ((blockIdx.x * 5) & 15) * 64;  // work-balance swizzle
  const int n = blockIdx.y, b = blockIdx.z;
  const size_t bn = (size_t)(b * 16 + n);
  const unsigned short* qwb = qw + bn * 1024 * 64;
  const unsigned short* qrb = qr + bn * 1024 * 64;
  const unsigned short* kb = kk + bn * 2048 * 64;
  const unsigned short* vb = vt + bn * 64 * 2048;
  const unsigned short* rb = rkp + (size_t)n * 2048 * 64;

  // resident Q fragments (A-operand: row = lr, k = g*8+e); pre-scaled by QSC
  const int qi = i0 + w * 16 + lr;
  s8v aqw[2], aqr[2];
#pragma unroll
  for (int ks = 0; ks < 2; ++ks) {
    aqw[ks] = *(const s8v*)(qwb + (size_t)qi * 64 + ks * 32 + g * 8);
    aqr[ks] = *(const s8v*)(qrb + (size_t)qi * 64 + ks * 32 + g * 8);
  }

  // all-ones bf16 B fragment for the denominator MFMA
  s8v ONES;
#pragma unroll
  for (int e = 0; e < 8; ++e) ONES[e] = (short)0x3F80;

  f4v acco[4] = {};
  f4v accl = {};                       // softmax denominator (replicated/lane)
  float mrow[4] = {-3e38f, -3e38f, -3e38f, -3e38f};

  const int ntile = (i0 + 1088) >> 6;

  auto stage = [&](int jt) {
    const int j0 = jt * 64;
    const int m0 = j0 + 960 - i0;
    // K [j][d]
#pragma unroll
    for (int ss = 0; ss < 2; ++ss) {
      int idx = w * 64 + ss * 256 + l;
      int row = idx >> 3, c = idx & 7;
      gl_lds16(kb + (size_t)(j0 + row) * 64 + ((c ^ (row & 7)) * 8),
               (void*)(Ks + (w * 64 + ss * 256) * 8));
    }
    // V^T [d][j]
#pragma unroll
    for (int ss = 0; ss < 2; ++ss) {
      int idx = w * 64 + ss * 256 + l;
      int d = idx >> 3, c = idx & 7;
      gl_lds16(vb + (size_t)d * 2048 + j0 + ((c ^ (d & 7)) * 8),
               (void*)(Vs + (w * 64 + ss * 256) * 8));
    }
    // RK band [m0..m0+127][d]
#pragma unroll
    for (int ss = 0; ss < 4; ++ss) {
      int idx = w * 64 + ss * 256 + l;
      int rr = idx >> 3, c = idx & 7;
      int m = m0 + rr;
      if (m > 2047) m = 2047;
      gl_lds16(rb + (size_t)m * 64 + ((c ^ (rr & 7)) * 8),
               (void*)(Rs + (w * 64 + ss * 256) * 8));
    }
  };

  for (int jt = 0; jt < ntile; ++jt) {
    const int j0 = jt * 64;
    stage(jt);
    __syncthreads();
    const bool mt = (jt == ntile - 1);  // only final tile can mask

    // ---- AC and E MFMAs ----
    f4v accs[4] = {};
    f4v acce[5] = {};
#pragma unroll
    for (int ks = 0; ks < 2; ++ks) {
#pragma unroll
      for (int jf = 0; jf < 4; ++jf) {
        int row = jf * 16 + lr;
        s8v bk =
            *(const s8v*)(Ks + row * 64 + (((ks * 4 + g) ^ (row & 7)) * 8));
        accs[jf] = MFMA(aqw[ks], bk, accs[jf]);
      }
#pragma unroll
      for (int ef = 0; ef < 5; ++ef) {
        int row = (3 - w + ef) * 16 + lr;
        s8v br =
            *(const s8v*)(Rs + row * 64 + (((ks * 4 + g) ^ (row & 7)) * 8));
        acce[ef] = MFMA(aqr[ks], br, acce[ef]);
      }
    }

    // ---- shift-extract E (5 dedup'd shuffles), defer-max softmax ----
    // score lane (g,lr), reg r: i = i0+w*16+4g+r, j = j0+jf*16+lr.
    // band row rr = (3-w+jf+carry)*16 + ((lr+s)&15), s = 15-4g-r.
    float P[4][4];
#pragma unroll
    for (int r = 0; r < 4; ++r) {
      const int s = 15 - 4 * g - r;           // in [0,15]
      const int src = (l & 48) | ((lr + s) & 15);
      const int carry = (lr + s) >> 4;
      float es[5];
#pragma unroll
      for (int f = 0; f < 5; ++f) es[f] = __shfl(acce[f][r], src, 64);
      float pmax = -3e38f;
#pragma unroll
      for (int jf = 0; jf < 4; ++jf) {
        float sv = accs[jf][r] + (carry ? es[jf + 1] : es[jf]);
        if (mt) {
          int jg = j0 + jf * 16 + lr;
          int ig = i0 + w * 16 + 4 * g + r;
          if (jg > ig + 1024) sv = -3e38f;
        }
        P[jf][r] = sv;
        pmax = fmaxf(pmax, sv);
      }
      if (!__all(pmax <= mrow[r] + 8.0f)) {   // rare after first tile
        float rmax = pmax;
#pragma unroll
        for (int dd = 1; dd < 16; dd <<= 1)
          rmax = fmaxf(rmax, __shfl_xor(rmax, dd, 64));
        float nm = fmaxf(mrow[r], rmax);
        float corr = exp2f(mrow[r] - nm);
        mrow[r] = nm;
#pragma unroll
        for (int df = 0; df < 4; ++df) acco[df][r] *= corr;
        accl[r] *= corr;
      }
#pragma unroll
      for (int jf = 0; jf < 4; ++jf) P[jf][r] = exp2f(P[jf][r] - mrow[r]);
    }

    // ---- P -> per-wave LDS [16 i][64 j], chunk-XOR swizzled ----
#pragma unroll
    for (int jf = 0; jf < 4; ++jf) {
#pragma unroll
      for (int r = 0; r < 4; ++r) {
        int ip = 4 * g + r;
        int cj = (jf * 2 + (lr >> 3)) ^ (ip & 7);
        Pn[w][ip * 64 + cj * 8 + (lr & 7)] = f2b(P[jf][r]);
      }
    }
    asm volatile("s_waitcnt lgkmcnt(0)" ::: "memory");
    __builtin_amdgcn_sched_barrier(0);

    // ---- PV + denominator: standard A/B fragment reads ----
#pragma unroll
    for (int ks = 0; ks < 2; ++ks) {
      s8v ap =
          *(const s8v*)(Pn[w] + lr * 64 + (((ks * 4 + g) ^ (lr & 7)) * 8));
      accl = MFMA(ap, ONES, accl);     // row-sum of P, replicated per lane
#pragma unroll
      for (int df = 0; df < 4; ++df) {
        int vrow = df * 16 + lr;
        s8v bv = *(const s8v*)(Vs + vrow * 64 +
                               (((ks * 4 + g) ^ (vrow & 7)) * 8));
        acco[df] = MFMA(ap, bv, acco[df]);
      }
    }
    __syncthreads();  // Ks/Vs/Rs/Pn safe to overwrite next tile
  }

  // ---- epilogue: O / l -> attn_vec bf16 [b*1024+i][n*64+d] ----
#pragma unroll
  for (int r = 0; r < 4; ++r) {
    float inv = 1.0f / accl[r];
    int ig = i0 + w * 16 + 4 * g + r;
#pragma unroll
    for (int df = 0; df < 4; ++df)
      av[((size_t)b * 1024 + ig) * 1024 + n * 64 + df * 16 + lr] =
          f2b(acco[df][r] * inv);
  }
}

// ---------------------------------------------------------------------------
extern "C" void kernel_launch(void* const* d_in, const int* in_sizes, int n_in,
                              void* d_out, int out_size, void* d_ws,
                              size_t ws_size, hipStream_t stream) {
  (void)in_sizes; (void)n_in; (void)out_size; (void)ws_size;
  const float* w   = (const float*)d_in[0];
  const float* r   = (const float*)d_in[1];
  const float* Wq  = (const float*)d_in[2];
  const float* Wkv = (const float*)d_in[3];
  const float* Wr  = (const float*)d_in[4];
  const float* Wo  = (const float*)d_in[5];
  const float* bw  = (const float*)d_in[6];
  const float* br  = (const float*)d_in[7];

  char* ws = (char*)d_ws;
  const size_t MB = 1024 * 1024;
  unsigned short* WqT  = (unsigned short*)(ws + 0 * MB);   // 2MB
  unsigned short* WkvT = (unsigned short*)(ws + 2 * MB);   // 4MB
  unsigned short* WrT  = (unsigned short*)(ws + 6 * MB);   // 2MB
  unsigned short* WoT  = (unsigned short*)(ws + 8 * MB);   // 2MB
  unsigned short* qwb  = (unsigned short*)(ws + 10 * MB);  // 8MB
  unsigned short* qrb  = (unsigned short*)(ws + 18 * MB);  // 8MB
  unsigned short* kbf  = (unsigned short*)(ws + 26 * MB);  // 16MB
  unsigned short* vbf  = (unsigned short*)(ws + 42 * MB);  // 16MB
  unsigned short* rkb  = (unsigned short*)(ws + 58 * MB);  // 4MB
  unsigned short* avb  = (unsigned short*)(ws + 62 * MB);  // 8MB (end 70MB)
  // V^T scratch: reuse d_out (16MB fp32 == 16MB needed; dead until gemm<3>).
  unsigned short* vtb  = (unsigned short*)d_out;

  hipLaunchKernelGGL(transpose_all, dim3(160, 32), dim3(32, 8), 0, stream,
                     Wq, Wkv, Wr, Wo, WqT, WkvT, WrT, WoT);

  hipLaunchKernelGGL((gemm_kern<0>), dim3(32, 8), dim3(256), 0, stream,
                     w, (const unsigned short*)nullptr, WqT, qwb, qrb,
                     (float*)nullptr, bw, br);
  hipLaunchKernelGGL((gemm_kern<1>), dim3(64, 16), dim3(256), 0, stream,
                     w, (const unsigned short*)nullptr, WkvT, kbf, vbf,
                     (float*)nullptr, (const float*)nullptr,
                     (const float*)nullptr);
  hipLaunchKernelGGL((gemm_kern<2>), dim3(16, 8), dim3(256), 0, stream,
                     r, (const unsigned short*)nullptr, WrT, rkb,
                     (unsigned short*)nullptr, (float*)nullptr,
                     (const float*)nullptr, (const float*)nullptr);

  hipLaunchKernelGGL(transpose_v, dim3(32, 64), dim3(256), 0, stream, vbf, vtb);

  hipLaunchKernelGGL(attn_kern, dim3(16, 16, 4), dim3(256), 0, stream,
                     qwb, qrb, kbf, vtb, rkb, avb);

  hipLaunchKernelGGL((gemm_kern<3>), dim3(32, 8), dim3(256), 0, stream,
                     (const float*)nullptr, avb, WoT, (unsigned short*)nullptr,
                     (unsigned short*)nullptr, (float*)d_out,
                     (const float*)nullptr, (const float*)nullptr);
}

// Round 13
// 425.174 us; speedup vs baseline: 1.7835x; 1.1650x over previous
//
#include <hip/hip_runtime.h>
#include <hip/hip_bf16.h>
#include <stdint.h>

// ============================================================================
// Transformer-XL relative attention, MI355X / gfx950.
// merged weight transpose -> Q/KV/R projection GEMMs (bf16 MFMA, fp32 accum,
// 2-phase double-buffered staging) -> V transpose -> flash attention with
// rel-shift band trick -> out GEMM.
// Attention: COMPLEMENTARY Q-TILE PAIRING -- block bx handles i0a=bx*64 and
// i0b=960-i0a. ntile(i0)=i0/64+17 so cost/block = const 49 tile-units:
// 512 uniform blocks = 2/CU all-resident, and each wave carries two
// independent dependency chains (2x ILP) sharing staged K/V.
// rel_shift(BD)[i,j] == BD[i, j + QLEN-1-i]; OOB exactly == masked region.
// q/qr are PRE-SCALED by (1/8)*log2(e) at projection time.
// NOTE: launch_bounds (256,2) permits <=256 VGPR; (256,4) forces 64 + spills.
// ============================================================================

#define DEVI static __device__ __forceinline__

typedef __attribute__((ext_vector_type(8))) short  s8v;   // 8 x bf16 (4 VGPR)
typedef __attribute__((ext_vector_type(4))) float  f4v;
typedef __attribute__((ext_vector_type(2))) int    i2v;
typedef __attribute__((ext_vector_type(4))) float  fl4;

DEVI unsigned short f2b(float f) {
  __hip_bfloat16 h = __float2bfloat16(f);
  return __builtin_bit_cast(unsigned short, h);
}

DEVI f4v MFMA(s8v a, s8v b, f4v c) {
  return __builtin_amdgcn_mfma_f32_16x16x32_bf16(a, b, c, 0, 0, 0);
}

// async global->LDS, 16B per lane. lds ptr must be wave-uniform base;
// HW adds lane*16. Global address is per-lane.
DEVI void gl_lds16(const void* g, void* lds) {
  __builtin_amdgcn_global_load_lds(
      (const __attribute__((address_space(1))) unsigned int*)g,
      (__attribute__((address_space(3))) unsigned int*)lds, 16, 0, 0);
}

// ---------------------------------------------------------------------------
// Merged transpose + bf16 convert for all four weights:
// W [1024=K][N] fp32 -> WT [N][1024] bf16. grid.x ranges select the matrix.
// ---------------------------------------------------------------------------
__global__ void transpose_all(const float* __restrict__ Wq,
                              const float* __restrict__ Wkv,
                              const float* __restrict__ Wr,
                              const float* __restrict__ Wo,
                              unsigned short* __restrict__ WqT,
                              unsigned short* __restrict__ WkvT,
                              unsigned short* __restrict__ WrT,
                              unsigned short* __restrict__ WoT) {
  __shared__ float tile[32][33];
  const int bx = blockIdx.x;
  const float* W;
  unsigned short* WT;
  int N, nb;
  if (bx < 32)       { W = Wq;  WT = WqT;  N = 1024; nb = bx; }
  else if (bx < 96)  { W = Wkv; WT = WkvT; N = 2048; nb = bx - 32; }
  else if (bx < 128) { W = Wr;  WT = WrT;  N = 1024; nb = bx - 96; }
  else               { W = Wo;  WT = WoT;  N = 1024; nb = bx - 128; }
  int n0 = nb * 32, k0 = blockIdx.y * 32;
  int tx = threadIdx.x, ty = threadIdx.y;  // 32 x 8
#pragma unroll
  for (int i = 0; i < 4; ++i)
    tile[ty + i * 8][tx] = W[(size_t)(k0 + ty + i * 8) * N + n0 + tx];
  __syncthreads();
#pragma unroll
  for (int i = 0; i < 4; ++i)
    WT[(size_t)(n0 + ty + i * 8) * 1024 + k0 + tx] = f2b(tile[tx][ty + i * 8]);
}

// ---------------------------------------------------------------------------
// V transpose: vbf [bh][2048 j][64 d] bf16 -> vt [bh][64 d][2048 j] bf16
// ---------------------------------------------------------------------------
__global__ void transpose_v(const unsigned short* __restrict__ in,
                            unsigned short* __restrict__ out) {
  __shared__ unsigned short Ts[64 * 72];
  const int t = threadIdx.x;
  const int j0 = blockIdx.x * 64;
  const size_t bh = blockIdx.y;
#pragma unroll
  for (int p = 0; p < 2; ++p) {
    int cc = t + p * 256;  // chunk id 0..511
    int j = cc >> 3, d0 = (cc & 7) * 8;
    s8v v = *(const s8v*)(in + (bh * 2048 + j0 + j) * 64 + d0);
    *(s8v*)(Ts + j * 72 + d0) = v;
  }
  __syncthreads();
  const int d = t >> 2, jc = (t & 3) * 16;
  s8v a, b;
#pragma unroll
  for (int e = 0; e < 8; ++e) a[e] = (short)Ts[(jc + e) * 72 + d];
#pragma unroll
  for (int e = 0; e < 8; ++e) b[e] = (short)Ts[(jc + 8 + e) * 72 + d];
  *(s8v*)(out + (bh * 64 + d) * 2048 + j0 + jc) = a;
  *(s8v*)(out + (bh * 64 + d) * 2048 + j0 + jc + 8) = b;
}

// ---------------------------------------------------------------------------
// GEMM: C[M][N] = A[M][1024] * B, B given as BT[N][1024] bf16.
// MODE 0: A=w tail rows, out qw/qr bf16 per-(b,head) [i][d] (+biases, *QSC)
// MODE 1: A=w,        out k/v bf16 per-(b,head) [j][d]
// MODE 2: A=r,        out rk bf16 per-head [m][d]
// MODE 3: A=attn_vec bf16, out fp32 d_out
// 128x128 tile, BK=32, 256 threads (4 waves, 2x2), 16x16x32 MFMA.
// 2-phase: stage(t+1) issued before compute(t); one barrier per K-step.
// ---------------------------------------------------------------------------
template <int MODE>
__global__ __launch_bounds__(256, 2) void gemm_kern(
    const float* __restrict__ A, const unsigned short* __restrict__ A16,
    const unsigned short* __restrict__ BT, unsigned short* __restrict__ O1,
    unsigned short* __restrict__ O2, float* __restrict__ Of,
    const float* __restrict__ biasw, const float* __restrict__ biasr) {
  __shared__ unsigned short As[2][128 * 32];
  __shared__ unsigned short Bs[2][128 * 32];
  const int t = threadIdx.x, l = t & 63, w = t >> 6;
  const int g = l >> 4, lr = l & 15;
  const int bm = blockIdx.x, bn = blockIdx.y;
  const int wr = w >> 1, wc = w & 1;
  const float QSC = 0.18033688f;  // (1/sqrt(64)) * log2(e)
  f4v acc[4][4] = {};

  auto stageB = [&](int k0, int buf) {
#pragma unroll
    for (int ss = 0; ss < 2; ++ss) {
      int idx = w * 64 + ss * 256 + l;
      int row = idx >> 2, c = idx & 3;
      gl_lds16(BT + (size_t)(bn * 128 + row) * 1024 + k0 + c * 8,
               (void*)(Bs[buf] + (w * 64 + ss * 256) * 8));
    }
  };
  auto stageA_lds = [&](int k0, int buf) {
#pragma unroll
    for (int ss = 0; ss < 2; ++ss) {
      int idx = w * 64 + ss * 256 + l;
      int row = idx >> 2, c = idx & 3;
      gl_lds16(A16 + (size_t)(bm * 128 + row) * 1024 + k0 + c * 8,
               (void*)(As[buf] + (w * 64 + ss * 256) * 8));
    }
  };
  auto loadA = [&](int k0, fl4* regs) {
#pragma unroll
    for (int ss = 0; ss < 4; ++ss) {
      int idx = t + ss * 256;
      int row = idx >> 3, c = idx & 7;
      int grow = bm * 128 + row;
      size_t arow = (MODE == 0)
                        ? ((size_t)(grow >> 10) * 2048 + 1024 + (grow & 1023))
                        : (size_t)grow;
      regs[ss] = *(const fl4*)(A + arow * 1024 + k0 + c * 4);
    }
  };
  auto writeA = [&](const fl4* regs, int buf) {
#pragma unroll
    for (int ss = 0; ss < 4; ++ss) {
      int idx = t + ss * 256;
      int row = idx >> 3, c = idx & 7;
      fl4 v = regs[ss];
      unsigned int p0 = f2b(v.x) | ((unsigned int)f2b(v.y) << 16);
      unsigned int p1 = f2b(v.z) | ((unsigned int)f2b(v.w) << 16);
      i2v pv; pv.x = (int)p0; pv.y = (int)p1;
      *(i2v*)(As[buf] + row * 32 + c * 4) = pv;
    }
  };

  // ---- prologue: stage k0=0 into buf 0 ----
  stageB(0, 0);
  if (MODE == 3) {
    stageA_lds(0, 0);
  } else {
    fl4 r0[4];
    loadA(0, r0);
    writeA(r0, 0);
  }
  __syncthreads();

  int cur = 0;
  for (int step = 0; step < 32; ++step) {
    const bool nx = step < 31;
    const int nk0 = (step + 1) * 32;
    fl4 aregs[4];
    if (nx) {
      stageB(nk0, cur ^ 1);
      if (MODE == 3) stageA_lds(nk0, cur ^ 1);
      else loadA(nk0, aregs);
    }
    s8v af[4], bf[4];
#pragma unroll
    for (int m = 0; m < 4; ++m)
      af[m] = *(const s8v*)(As[cur] + (wr * 64 + m * 16 + lr) * 32 + g * 8);
#pragma unroll
    for (int n = 0; n < 4; ++n)
      bf[n] = *(const s8v*)(Bs[cur] + (wc * 64 + n * 16 + lr) * 32 + g * 8);
#pragma unroll
    for (int m = 0; m < 4; ++m)
#pragma unroll
      for (int n = 0; n < 4; ++n) acc[m][n] = MFMA(af[m], bf[n], acc[m][n]);
    if (nx && MODE != 3) writeA(aregs, cur ^ 1);
    __syncthreads();
    cur ^= 1;
  }

  // ---- epilogue ----
#pragma unroll
  for (int m = 0; m < 4; ++m) {
#pragma unroll
    for (int n = 0; n < 4; ++n) {
#pragma unroll
      for (int r = 0; r < 4; ++r) {
        int row = bm * 128 + wr * 64 + m * 16 + g * 4 + r;
        int col = bn * 128 + wc * 64 + n * 16 + lr;
        float v = acc[m][n][r];
        if (MODE == 0) {
          int b = row >> 10, i = row & 1023;
          int nh = col >> 6, d = col & 63;
          size_t o = ((size_t)(b * 16 + nh) * 1024 + i) * 64 + d;
          O1[o] = f2b((v + biasw[col]) * QSC);
          O2[o] = f2b((v + biasr[col]) * QSC);
        } else if (MODE == 1) {
          int b = row >> 11, j = row & 2047;
          if (col < 1024)
            O1[((size_t)(b * 16 + (col >> 6)) * 2048 + j) * 64 + (col & 63)] =
                f2b(v);
          else
            O2[((size_t)(b * 16 + ((col - 1024) >> 6)) * 2048 + j) * 64 +
               (col & 63)] = f2b(v);
        } else if (MODE == 2) {
          O1[((size_t)(col >> 6) * 2048 + row) * 64 + (col & 63)] = f2b(v);
        } else {
          Of[(size_t)row * 1024 + col] = v;
        }
      }
    }
  }
}

// ---------------------------------------------------------------------------
// Flash attention with rel-shift, complementary q-tile pairing.
// Block = (pair bx in 0..7, head, batch): q-tiles i0a=bx*64, i0b=960-i0a.
// nta=bx+17, ntb=32-bx (nta<=ntb); loop jt 0..ntb-1: phase A while jt<nta,
// phase B always. K/V staged once per tile, shared by both phases.
// Per phase: AC = qw.K^T; E = qr.rk_band^T (5 frags, 80-wide);
// score = AC + shifted E (q pre-scaled); defer-max online softmax;
// P -> per-wave LDS; O += P.V; denominator via ones-MFMA.
// m0a = j0+960-i0a, m0b = j0+i0a; clamp m<=2047 (only masked scores).
// Mask active only on each phase's final tile.
// ---------------------------------------------------------------------------
__global__ __launch_bounds__(256, 2) void attn_kern(
    const unsigned short* __restrict__ qw, const unsigned short* __restrict__ qr,
    const unsigned short* __restrict__ kk, const unsigned short* __restrict__ vt,
    const unsigned short* __restrict__ rkp, unsigned short* __restrict__ av) {
  __shared__ unsigned short Ks[64 * 64];    // [j][d], chunk-XOR swizzled
  __shared__ unsigned short Vs[64 * 64];    // [d][j] (V^T tile), swizzled
  __shared__ unsigned short Ra[128 * 64];   // A band [m][d], swizzled
  __shared__ unsigned short Rb[128 * 64];   // B band [m][d], swizzled
  __shared__ unsigned short Pa[4][1024];    // per-wave P_A [16 i][64 j], swz
  __shared__ unsigned short Pb[4][1024];    // per-wave P_B
  const int t = threadIdx.x, l = t & 63, w = t >> 6;
  const int g = l >> 4, lr = l & 15;
  const int bx = blockIdx.x;                 // 0..7
  const int i0a = bx * 64, i0b = 960 - i0a;
  const int nta = bx + 17, ntb = 32 - bx;
  const int n = blockIdx.y, b = blockIdx.z;
  const size_t bn = (size_t)(b * 16 + n);
  const unsigned short* qwb = qw + bn * 1024 * 64;
  const unsigned short* qrb = qr + bn * 1024 * 64;
  const unsigned short* kb = kk + bn * 2048 * 64;
  const unsigned short* vb = vt + bn * 64 * 2048;
  const unsigned short* rb = rkp + (size_t)n * 2048 * 64;

  // resident Q fragments for both q-tiles (A-operand: row=lr, k=g*8+e)
  const int qia = i0a + w * 16 + lr;
  const int qib = i0b + w * 16 + lr;
  s8v aqw_a[2], aqr_a[2], aqw_b[2], aqr_b[2];
#pragma unroll
  for (int ks = 0; ks < 2; ++ks) {
    aqw_a[ks] = *(const s8v*)(qwb + (size_t)qia * 64 + ks * 32 + g * 8);
    aqr_a[ks] = *(const s8v*)(qrb + (size_t)qia * 64 + ks * 32 + g * 8);
    aqw_b[ks] = *(const s8v*)(qwb + (size_t)qib * 64 + ks * 32 + g * 8);
    aqr_b[ks] = *(const s8v*)(qrb + (size_t)qib * 64 + ks * 32 + g * 8);
  }

  s8v ONES;
#pragma unroll
  for (int e = 0; e < 8; ++e) ONES[e] = (short)0x3F80;

  f4v acco_a[4] = {}, acco_b[4] = {};
  f4v accl_a = {}, accl_b = {};
  float mrow_a[4] = {-3e38f, -3e38f, -3e38f, -3e38f};
  float mrow_b[4] = {-3e38f, -3e38f, -3e38f, -3e38f};

  auto stageR = [&](unsigned short* Rx, int m0) {
#pragma unroll
    for (int ss = 0; ss < 4; ++ss) {
      int idx = w * 64 + ss * 256 + l;
      int rr = idx >> 3, c = idx & 7;
      int m = m0 + rr;
      if (m > 2047) m = 2047;
      gl_lds16(rb + (size_t)m * 64 + ((c ^ (rr & 7)) * 8),
               (void*)(Rx + (w * 64 + ss * 256) * 8));
    }
  };

  auto stage = [&](int jt) {
    const int j0 = jt * 64;
    // K [j][d]
#pragma unroll
    for (int ss = 0; ss < 2; ++ss) {
      int idx = w * 64 + ss * 256 + l;
      int row = idx >> 3, c = idx & 7;
      gl_lds16(kb + (size_t)(j0 + row) * 64 + ((c ^ (row & 7)) * 8),
               (void*)(Ks + (w * 64 + ss * 256) * 8));
    }
    // V^T [d][j]
#pragma unroll
    for (int ss = 0; ss < 2; ++ss) {
      int idx = w * 64 + ss * 256 + l;
      int d = idx >> 3, c = idx & 7;
      gl_lds16(vb + (size_t)d * 2048 + j0 + ((c ^ (d & 7)) * 8),
               (void*)(Vs + (w * 64 + ss * 256) * 8));
    }
    if (jt < nta) stageR(Ra, j0 + 960 - i0a);
    stageR(Rb, j0 + i0a);
  };

  // One phase: AC/E MFMAs, shift-extract, defer-max softmax, P->LDS, PV.
  auto phase = [&](const unsigned short* Rx, unsigned short* Px,
                   const s8v* paqw, const s8v* paqr, f4v* acco, f4v& accl,
                   float* mrow, bool mt, int i0, int j0) {
    f4v accs[4] = {};
    f4v acce[5] = {};
#pragma unroll
    for (int ks = 0; ks < 2; ++ks) {
#pragma unroll
      for (int jf = 0; jf < 4; ++jf) {
        int row = jf * 16 + lr;
        s8v bk =
            *(const s8v*)(Ks + row * 64 + (((ks * 4 + g) ^ (row & 7)) * 8));
        accs[jf] = MFMA(paqw[ks], bk, accs[jf]);
      }
#pragma unroll
      for (int ef = 0; ef < 5; ++ef) {
        int row = (3 - w + ef) * 16 + lr;
        s8v br =
            *(const s8v*)(Rx + row * 64 + (((ks * 4 + g) ^ (row & 7)) * 8));
        acce[ef] = MFMA(paqr[ks], br, acce[ef]);
      }
    }

    // shift-extract: lane (g,lr), reg r: i=i0+w*16+4g+r, j=j0+jf*16+lr;
    // band row rr=(3-w+jf+carry)*16+((lr+s)&15), s=15-4g-r.
    float P[4][4];
#pragma unroll
    for (int r = 0; r < 4; ++r) {
      const int s = 15 - 4 * g - r;           // in [0,15]
      const int src = (l & 48) | ((lr + s) & 15);
      const int carry = (lr + s) >> 4;
      float es[5];
#pragma unroll
      for (int f = 0; f < 5; ++f) es[f] = __shfl(acce[f][r], src, 64);
      float pmax = -3e38f;
#pragma unroll
      for (int jf = 0; jf < 4; ++jf) {
        float sv = accs[jf][r] + (carry ? es[jf + 1] : es[jf]);
        if (mt) {
          int jg = j0 + jf * 16 + lr;
          int ig = i0 + w * 16 + 4 * g + r;
          if (jg > ig + 1024) sv = -3e38f;
        }
        P[jf][r] = sv;
        pmax = fmaxf(pmax, sv);
      }
      if (!__all(pmax <= mrow[r] + 8.0f)) {   // rare after first tile
        float rmax = pmax;
#pragma unroll
        for (int dd = 1; dd < 16; dd <<= 1)
          rmax = fmaxf(rmax, __shfl_xor(rmax, dd, 64));
        float nm = fmaxf(mrow[r], rmax);
        float corr = exp2f(mrow[r] - nm);
        mrow[r] = nm;
#pragma unroll
        for (int df = 0; df < 4; ++df) acco[df][r] *= corr;
        accl[r] *= corr;
      }
#pragma unroll
      for (int jf = 0; jf < 4; ++jf) P[jf][r] = exp2f(P[jf][r] - mrow[r]);
    }

    // P -> per-wave LDS [16 i][64 j], chunk-XOR swizzled
#pragma unroll
    for (int jf = 0; jf < 4; ++jf) {
#pragma unroll
      for (int r = 0; r < 4; ++r) {
        int ip = 4 * g + r;
        int cj = (jf * 2 + (lr >> 3)) ^ (ip & 7);
        Px[ip * 64 + cj * 8 + (lr & 7)] = f2b(P[jf][r]);
      }
    }
    asm volatile("s_waitcnt lgkmcnt(0)" ::: "memory");
    __builtin_amdgcn_sched_barrier(0);

    // PV + denominator
#pragma unroll
    for (int ks = 0; ks < 2; ++ks) {
      s8v ap = *(const s8v*)(Px + lr * 64 + (((ks * 4 + g) ^ (lr & 7)) * 8));
      accl = MFMA(ap, ONES, accl);
#pragma unroll
      for (int df = 0; df < 4; ++df) {
        int vrow = df * 16 + lr;
        s8v bv = *(const s8v*)(Vs + vrow * 64 +
                               (((ks * 4 + g) ^ (vrow & 7)) * 8));
        acco[df] = MFMA(ap, bv, acco[df]);
      }
    }
  };

  for (int jt = 0; jt < ntb; ++jt) {
    const int j0 = jt * 64;
    stage(jt);
    __syncthreads();
    if (jt < nta)
      phase(Ra, Pa[w], aqw_a, aqr_a, acco_a, accl_a, mrow_a,
            jt == nta - 1, i0a, j0);
    phase(Rb, Pb[w], aqw_b, aqr_b, acco_b, accl_b, mrow_b,
          jt == ntb - 1, i0b, j0);
    __syncthreads();  // LDS safe to overwrite next tile
  }

  // ---- epilogue: O / l -> attn_vec bf16 [b*1024+i][n*64+d] ----
#pragma unroll
  for (int r = 0; r < 4; ++r) {
    float inva = 1.0f / accl_a[r];
    float invb = 1.0f / accl_b[r];
    int iga = i0a + w * 16 + 4 * g + r;
    int igb = i0b + w * 16 + 4 * g + r;
#pragma unroll
    for (int df = 0; df < 4; ++df) {
      av[((size_t)b * 1024 + iga) * 1024 + n * 64 + df * 16 + lr] =
          f2b(acco_a[df][r] * inva);
      av[((size_t)b * 1024 + igb) * 1024 + n * 64 + df * 16 + lr] =
          f2b(acco_b[df][r] * invb);
    }
  }
}

// ---------------------------------------------------------------------------
extern "C" void kernel_launch(void* const* d_in, const int* in_sizes, int n_in,
                              void* d_out, int out_size, void* d_ws,
                              size_t ws_size, hipStream_t stream) {
  (void)in_sizes; (void)n_in; (void)out_size; (void)ws_size;
  const float* w   = (const float*)d_in[0];
  const float* r   = (const float*)d_in[1];
  const float* Wq  = (const float*)d_in[2];
  const float* Wkv = (const float*)d_in[3];
  const float* Wr  = (const float*)d_in[4];
  const float* Wo  = (const float*)d_in[5];
  const float* bw  = (const float*)d_in[6];
  const float* br  = (const float*)d_in[7];

  char* ws = (char*)d_ws;
  const size_t MB = 1024 * 1024;
  unsigned short* WqT  = (unsigned short*)(ws + 0 * MB);   // 2MB
  unsigned short* WkvT = (unsigned short*)(ws + 2 * MB);   // 4MB
  unsigned short* WrT  = (unsigned short*)(ws + 6 * MB);   // 2MB
  unsigned short* WoT  = (unsigned short*)(ws + 8 * MB);   // 2MB
  unsigned short* qwb  = (unsigned short*)(ws + 10 * MB);  // 8MB
  unsigned short* qrb  = (unsigned short*)(ws + 18 * MB);  // 8MB
  unsigned short* kbf  = (unsigned short*)(ws + 26 * MB);  // 16MB
  unsigned short* vbf  = (unsigned short*)(ws + 42 * MB);  // 16MB
  unsigned short* rkb  = (unsigned short*)(ws + 58 * MB);  // 4MB
  unsigned short* avb  = (unsigned short*)(ws + 62 * MB);  // 8MB (end 70MB)
  // V^T scratch: reuse d_out (16MB fp32 == 16MB needed; dead until gemm<3>).
  unsigned short* vtb  = (unsigned short*)d_out;

  hipLaunchKernelGGL(transpose_all, dim3(160, 32), dim3(32, 8), 0, stream,
                     Wq, Wkv, Wr, Wo, WqT, WkvT, WrT, WoT);

  hipLaunchKernelGGL((gemm_kern<0>), dim3(32, 8), dim3(256), 0, stream,
                     w, (const unsigned short*)nullptr, WqT, qwb, qrb,
                     (float*)nullptr, bw, br);
  hipLaunchKernelGGL((gemm_kern<1>), dim3(64, 16), dim3(256), 0, stream,
                     w, (const unsigned short*)nullptr, WkvT, kbf, vbf,
                     (float*)nullptr, (const float*)nullptr,
                     (const float*)nullptr);
  hipLaunchKernelGGL((gemm_kern<2>), dim3(16, 8), dim3(256), 0, stream,
                     r, (const unsigned short*)nullptr, WrT, rkb,
                     (unsigned short*)nullptr, (float*)nullptr,
                     (const float*)nullptr, (const float*)nullptr);

  hipLaunchKernelGGL(transpose_v, dim3(32, 64), dim3(256), 0, stream, vbf, vtb);

  hipLaunchKernelGGL(attn_kern, dim3(8, 16, 4), dim3(256), 0, stream,
                     qwb, qrb, kbf, vtb, rkb, avb);

  hipLaunchKernelGGL((gemm_kern<3>), dim3(32, 8), dim3(256), 0, stream,
                     (const float*)nullptr, avb, WoT, (unsigned short*)nullptr,
                     (unsigned short*)nullptr, (float*)d_out,
                     (const float*)nullptr, (const float*)nullptr);
}